// Round 8
// baseline (3592.709 us; speedup 1.0000x reference)
//
#include <hip/hip_runtime.h>
#include <hip/hip_bf16.h>

// Kokoro TTS forward, fused bf16-MFMA pipeline.
// B=8, T_TEXT=256, T_MEL=1024, H=512, MEL=80, NH=8, HD=64.
// All linears: one MFMA GEMM kernel (C = alpha*A@B^T + bias), A/B bf16, acc fp32.
// LSTM recurrences: persistent kernels (1 WG/CU). Tag-in-word dataflow at
// AGENT scope: each h-pair is one relaxed agent u64 {pair(lo32), step(hi32)};
// producers fire-and-forget; every compute thread polls its own words, packs
// to LDS, one __syncthreads, MFMA with W_hh in VGPRs (R7: 1800us dec).
// R8: EARLY SPECULATIVE POLL. R7's poll issues at the top of step s (just
// after our own store), so round 1 nearly always misses -> discovery = 1-2
// full MALL RTTs serialized after compute (FETCH showed ~2 reads/word).
// Now a speculative round for h(s+1) issues right after the MFMA of step s
// and flies under nonlin+store+loop; the top-of-step check usually finds it
// hit. Own-WG words can't hit an early round (not yet stored), so they skip
// the global loop entirely: the nonlin writer drops its pair directly into
// h_s[(s+1)&1] (safe: every wave passed MFMA(s-1) -- the last reader of that
// buffer -- at barrier(s)); polls/packs skip own pairs via the ownm mask.
// Re-polls reload only still-stale pairs.
// Gate rows permuted rho(G,u)=4u+G so each 16-wide n-tile = 4 units x 4 gates.

typedef unsigned short u16;
typedef unsigned int u32;
typedef unsigned long long u64;
typedef short short8 __attribute__((ext_vector_type(8)));
typedef float float4_ __attribute__((ext_vector_type(4)));

__device__ __forceinline__ u16 f2b16(float f) {
  u32 u = __float_as_uint(f);
  u = (u + 0x7FFF + ((u >> 16) & 1)) >> 16;
  return (u16)u;
}
__device__ __forceinline__ float b2f(u16 h) { return __uint_as_float((u32)h << 16); }
__device__ __forceinline__ float sigm(float x) { return 1.f / (1.f + __expf(-x)); }
__device__ __forceinline__ float tanh_(float x) { return 2.f / (1.f + __expf(-2.f * x)) - 1.f; }

// ---------------- small conversion kernels ----------------
__global__ void f2b_k(const float* __restrict__ s, u16* __restrict__ d, int n) {
  for (int i = blockIdx.x * 256 + threadIdx.x; i < n; i += gridDim.x * 256) d[i] = f2b16(s[i]);
}
// LSTM weight rows [2048,K]: out row r=4u+G <- src row G*512+u, f32->bf16
__global__ void permconv_k(const float* __restrict__ s, u16* __restrict__ d, int K) {
  int row = blockIdx.x; int u = row >> 2, G = row & 3;
  const float* sr = s + (long)(G * 512 + u) * K;
  u16* dr = d + (long)row * K;
  for (int c = threadIdx.x; c < K; c += 256) dr[c] = f2b16(sr[c]);
}
__global__ void biascomb_k(const float* __restrict__ bih, const float* __restrict__ bhh,
                           float* __restrict__ out) {
  int r = blockIdx.x * 256 + threadIdx.x; // 2048
  int u = r >> 2, G = r & 3;
  out[r] = bih[G * 512 + u] + bhh[G * 512 + u];
}
// mel_in_w [512,80] -> [512,128] zero-padded bf16
__global__ void melinw_k(const float* __restrict__ s, u16* __restrict__ d) {
  int row = blockIdx.x, c = threadIdx.x; // block 128
  d[row * 128 + c] = (c < 80) ? f2b16(s[row * 80 + c]) : (u16)0;
}
// mel_out_w [80,512] -> [128,512] zero row-padded bf16
__global__ void meloutw_k(const float* __restrict__ s, u16* __restrict__ d) {
  int row = blockIdx.x;
  for (int c = threadIdx.x; c < 512; c += 256)
    d[row * 512 + c] = (row < 80) ? f2b16(s[row * 512 + c]) : (u16)0;
}
__global__ void biaspad_k(const float* __restrict__ s, float* __restrict__ d) {
  int t = threadIdx.x; // 128
  d[t] = (t < 80) ? s[t] : 0.f;
}
// embedding gather -> bf16 [8,256,512]
__global__ void embed_k(const int* __restrict__ pid, const float* __restrict__ emb,
                        u16* __restrict__ x) {
  int t = blockIdx.x, b = blockIdx.y;
  int row = pid[b * 256 + t];
  const float* e = emb + (long)row * 512;
  u16* xr = x + ((long)b * 256 + t) * 512;
  xr[threadIdx.x] = f2b16(e[threadIdx.x]);
  xr[threadIdx.x + 256] = f2b16(e[threadIdx.x + 256]);
}
// mel shift + pad K 80->128 -> bf16 [8,1024,128]
__global__ void melin_k(const float* __restrict__ mel, u16* __restrict__ out) {
  int t = blockIdx.x, b = blockIdx.y, c = threadIdx.x; // block 128
  float v = (c < 80 && t > 0) ? mel[((long)b * 1024 + (t - 1)) * 80 + c] : 0.f;
  out[((long)b * 1024 + t) * 128 + c] = f2b16(v);
}
// per-batch duration cumsum (values are exact small ints)
__global__ void cumsum_k(const float* __restrict__ dur, int* __restrict__ cum,
                         int* __restrict__ Lb) {
  int b = blockIdx.x, t = threadIdx.x;
  __shared__ int sd[256];
  sd[t] = __float2int_rn(dur[b * 256 + t]);
  __syncthreads();
  for (int o = 1; o < 256; o <<= 1) {
    int v = (t >= o) ? sd[t - o] : 0;
    __syncthreads();
    sd[t] += v;
    __syncthreads();
  }
  cum[b * 256 + t] = sd[t];
  if (t == 255) Lb[b] = min(sd[255], 1024);
}
// length-regulate gather: exp[b,pos,:] = pad ? 0 : enc[b,idx,:]
__global__ void gather_k(const int* __restrict__ cum, const u16* __restrict__ enc,
                         u16* __restrict__ exp_) {
  int pos = blockIdx.x, b = blockIdx.y;
  const int* cb = cum + b * 256;
  int last = cb[255];
  u32 val = 0;
  if (pos < last) {
    int lo = 0, hi = 255;
    while (lo < hi) { int mid = (lo + hi) >> 1; if (cb[mid] > pos) hi = mid; else lo = mid + 1; }
    val = ((const u32*)(enc + ((long)b * 256 + lo) * 512))[threadIdx.x];
  }
  ((u32*)(exp_ + ((long)b * 1024 + pos) * 512))[threadIdx.x] = val;
}
// row softmax over [0,L) with bf16 P output (zeros beyond L)
__global__ void softmax_k(const float* __restrict__ sbuf, u16* __restrict__ P,
                          const int* __restrict__ Lb) {
  int qp = blockIdx.x, b = blockIdx.y;
  const float* s = sbuf + ((long)b * 1024 + qp) * 1024;
  u16* p = P + ((long)b * 1024 + qp) * 1024;
  int L = Lb[b];
  __shared__ float red[256];
  int tid = threadIdx.x;
  float m = -1e30f;
  for (int i = tid; i < L; i += 256) m = fmaxf(m, s[i]);
  red[tid] = m; __syncthreads();
  for (int o = 128; o > 0; o >>= 1) { if (tid < o) red[tid] = fmaxf(red[tid], red[tid + o]); __syncthreads(); }
  float mx = red[0];
  __syncthreads();
  float sm = 0.f;
  for (int i = tid; i < L; i += 256) sm += __expf(s[i] - mx);
  red[tid] = sm; __syncthreads();
  for (int o = 128; o > 0; o >>= 1) { if (tid < o) red[tid] += red[tid + o]; __syncthreads(); }
  float inv = 1.f / red[0];
  for (int i = tid; i < 1024; i += 256) {
    float v = (i < L) ? __expf(s[i] - mx) * inv : 0.f;
    p[i] = f2b16(v);
  }
}
// log_dur = h2 @ w3^T + b3  (K=256, N=1), fp32
__global__ void dur3_k(const u16* __restrict__ h2, const float* __restrict__ w3,
                       const float* __restrict__ b3, float* __restrict__ out) {
  int row = blockIdx.x * 4 + (threadIdx.x >> 6);
  int l = threadIdx.x & 63;
  const u16* hr = h2 + (long)row * 256;
  float s = 0.f;
  for (int i = 0; i < 4; i++) { int c = l * 4 + i; s += b2f(hr[c]) * w3[c]; }
  for (int o = 32; o > 0; o >>= 1) s += __shfl_down(s, o);
  if (l == 0) out[row] = s + b3[0];
}

// ---------------- GEMM: C[M,N] = alpha * A[M,K] @ B[N,K]^T (+bias[n]) ----------------
// flags: 1 = store bf16, 2 = relu, 4 = transposed C store (addr = n*ldc + m)
// A split option: k < ksplit from A, else from A2 (for dec_in concat).
// tiles 128x128xBK64, 256 thr, 4 waves 2x2, each wave 4x4 of mfma 16x16x32 bf16.
__global__ __launch_bounds__(256) void gemm_bt(
    const u16* __restrict__ A, const u16* __restrict__ A2, int ksplit, int lda, int lda2, long sA,
    const u16* __restrict__ B, int ldb, long sB, void* __restrict__ Cv, int ldc, long sC,
    const float* __restrict__ bias, float alpha, int N, int K, int flags) {
  __shared__ u16 As[128 * 72];
  __shared__ u16 Bs[128 * 72];
  int z = blockIdx.z;
  const u16* Ab = A + (long)z * sA;
  const u16* A2b = A2 ? (A2 + (long)z * sA) : (const u16*)0;
  const u16* Bb = B + (long)z * sB;
  int m0 = blockIdx.x * 128, n0 = blockIdx.y * 128;
  int tid = threadIdx.x, wave = tid >> 6, lane = tid & 63;
  int wm = wave & 1, wn = wave >> 1;
  int nl = lane & 15, kb = (lane >> 4) * 8, ml = (lane >> 4) * 4;
  float4_ acc[4][4];
  for (int i = 0; i < 4; i++)
    for (int j = 0; j < 4; j++) { acc[i][j][0] = 0; acc[i][j][1] = 0; acc[i][j][2] = 0; acc[i][j][3] = 0; }
  int rr = tid >> 3, cc = (tid & 7) * 8;
  for (int k0 = 0; k0 < K; k0 += 64) {
    int gk = k0 + cc;
#pragma unroll
    for (int i = 0; i < 4; i++) {
      int row = rr + i * 32;
      const u16* sa = (gk < ksplit) ? (Ab + (long)(m0 + row) * lda + gk)
                                    : (A2b + (long)(m0 + row) * lda2 + (gk - ksplit));
      *(short8*)&As[row * 72 + cc] = *(const short8*)sa;
      *(short8*)&Bs[row * 72 + cc] = *(const short8*)(Bb + (long)(n0 + row) * ldb + gk);
    }
    __syncthreads();
#pragma unroll
    for (int kk = 0; kk < 64; kk += 32) {
      short8 af[4], bfr[4];
#pragma unroll
      for (int i = 0; i < 4; i++) af[i] = *(const short8*)&As[(wm * 64 + i * 16 + nl) * 72 + kk + kb];
#pragma unroll
      for (int i = 0; i < 4; i++) bfr[i] = *(const short8*)&Bs[(wn * 64 + i * 16 + nl) * 72 + kk + kb];
#pragma unroll
      for (int mi = 0; mi < 4; mi++)
#pragma unroll
        for (int ni = 0; ni < 4; ni++)
          acc[mi][ni] = __builtin_amdgcn_mfma_f32_16x16x32_bf16(af[mi], bfr[ni], acc[mi][ni], 0, 0, 0);
    }
    __syncthreads();
  }
  for (int ni = 0; ni < 4; ni++) {
    int n = n0 + wn * 64 + ni * 16 + nl;
    if (n >= N) continue;
    float bv = bias ? bias[n] : 0.f;
    for (int mi = 0; mi < 4; mi++) {
#pragma unroll
      for (int r = 0; r < 4; r++) {
        int m = m0 + wm * 64 + mi * 16 + ml + r;
        float v = acc[mi][ni][r] * alpha + bv;
        if (flags & 2) v = fmaxf(v, 0.f);
        long idx = (flags & 4) ? ((long)n * ldc + m) : ((long)m * ldc + n);
        if (flags & 1) ((u16*)Cv)[z * sC + idx] = f2b16(v);
        else ((float*)Cv)[z * sC + idx] = v;
      }
    }
  }
}

// ---------------- persistent LSTM recurrences ----------------
// hglob: u64[2][8][256] per team, word = {pair(lo32), step(hi32)}.
// Thread (prow=tid>>5, c32=tid&31) owns 4 pair-groups j: global slots
// {j*64+2*c32, +1} of row prow. Own-WG groups (slot>>3 == wg) skip the
// global path: nonlin writes them straight into h_s. Speculative round for
// h(s+1) issues after MFMA(s); top-of-step check re-polls only stale pairs.

// Encoder: 64 WGs (dir = bid>>5), 256 steps. hglob: u64[dir][2][8][256].
__global__ __launch_bounds__(256) void enc_rec_k(
    const float* __restrict__ xg_f, const float* __restrict__ xg_b,
    const u16* __restrict__ whh_f, const u16* __restrict__ whh_b,
    u16* __restrict__ hcat, u64* __restrict__ hglob) {
  int dir = blockIdx.x >> 5, wg = blockIdx.x & 31;
  int tid = threadIdx.x, wave = tid >> 6, lane = tid & 63;
  int nl = lane & 15, kb = (lane >> 4) * 8, ml = (lane >> 4) * 4;
  int nt = wg * 4 + wave;
  const float* xg = dir ? xg_b : xg_f;
  const u16* whh = dir ? whh_b : whh_f;
  u64* hg = hglob + dir * 4096;
  __shared__ u16 h_s[2][16 * 520];
  __shared__ float gbuf[4][16][17];
  __shared__ float c_s[4][4][8];
  short8 warr[16];
  {
    const u16* wr = whh + (long)(wg * 64 + wave * 16 + nl) * 512 + kb;
#pragma unroll
    for (int kc = 0; kc < 16; kc++) warr[kc] = *(const short8*)(wr + kc * 32);
  }
  if (lane < 32) c_s[wave][lane & 3][lane >> 2] = 0.f;
  __syncthreads();
  float nxt[4];
  {
    int t0 = dir ? 255 : 0;
#pragma unroll
    for (int r = 0; r < 4; r++) {
      int m = ml + r;
      nxt[r] = (m < 8) ? xg[((long)m * 256 + t0) * 2048 + nt * 16 + nl] : 0.f;
    }
  }
  int prow = tid >> 5, c32 = tid & 31;
  u32 ownm = 0;
#pragma unroll
  for (int j = 0; j < 4; j++)
    if (((j * 64 + c32 * 2) >> 3) == wg) ownm |= 1u << j;
  u64 a[8];
  for (int s = 0; s < 256; ++s) {
    int t = dir ? 255 - s : s;
    int pb = s & 1;
    float cur0 = nxt[0], cur1 = nxt[1], cur2 = nxt[2], cur3 = nxt[3];
    if (s > 0) {  // finalize discovery: check speculative round, re-poll stale
      const u64* hp = hg + (long)pb * 2048 + prow * 256 + c32 * 2;
      u32 tg = (u32)s;
      for (;;) {
        u32 bad = 0;
#pragma unroll
        for (int j = 0; j < 4; j++)
          if (!((ownm >> j) & 1))
            bad |= ((u32)(a[2 * j] >> 32) ^ tg) | ((u32)(a[2 * j + 1] >> 32) ^ tg);
        if (!bad) break;
#pragma unroll
        for (int j = 0; j < 4; j++)
          if (!((ownm >> j) & 1) &&
              ((((u32)(a[2 * j] >> 32)) ^ tg) | (((u32)(a[2 * j + 1] >> 32)) ^ tg))) {
            a[2 * j] = __hip_atomic_load(hp + j * 64, __ATOMIC_RELAXED, __HIP_MEMORY_SCOPE_AGENT);
            a[2 * j + 1] =
                __hip_atomic_load(hp + j * 64 + 1, __ATOMIC_RELAXED, __HIP_MEMORY_SCOPE_AGENT);
          }
      }
      u64* dp = (u64*)(h_s[pb] + prow * 520);
#pragma unroll
      for (int j = 0; j < 4; j++)
        if (!((ownm >> j) & 1))
          dp[c32 + j * 32] = (a[2 * j] & 0xffffffffull) | (a[2 * j + 1] << 32);
    }
    __builtin_amdgcn_sched_barrier(0);  // prefetch issue stays AFTER the check
    if (s + 1 < 256) {
      int tn = dir ? 255 - (s + 1) : (s + 1);
#pragma unroll
      for (int r = 0; r < 4; r++) {
        int m = ml + r;
        nxt[r] = (m < 8) ? xg[((long)m * 256 + tn) * 2048 + nt * 16 + nl] : 0.f;
      }
    }
    __syncthreads();  // pack + own-LDS writes visible -> MFMA
    float4_ ac0, ac1, ac2, ac3;
    ac0[0] = cur0; ac0[1] = cur1; ac0[2] = cur2; ac0[3] = cur3;
    ac1[0] = 0; ac1[1] = 0; ac1[2] = 0; ac1[3] = 0;
    ac2 = ac1; ac3 = ac1;
    if (s > 0) {
      const u16* hrow = h_s[pb] + nl * 520 + kb;
#pragma unroll
      for (int kc = 0; kc < 16; kc += 4) {
        ac0 = __builtin_amdgcn_mfma_f32_16x16x32_bf16(
            *(const short8*)(hrow + (kc + 0) * 32), warr[kc + 0], ac0, 0, 0, 0);
        ac1 = __builtin_amdgcn_mfma_f32_16x16x32_bf16(
            *(const short8*)(hrow + (kc + 1) * 32), warr[kc + 1], ac1, 0, 0, 0);
        ac2 = __builtin_amdgcn_mfma_f32_16x16x32_bf16(
            *(const short8*)(hrow + (kc + 2) * 32), warr[kc + 2], ac2, 0, 0, 0);
        ac3 = __builtin_amdgcn_mfma_f32_16x16x32_bf16(
            *(const short8*)(hrow + (kc + 3) * 32), warr[kc + 3], ac3, 0, 0, 0);
      }
    }
    float4_ acc = (ac0 + ac1) + (ac2 + ac3);
    // speculative poll round for h(s+1): flies under nonlin+store+loop-top
    if (s + 1 < 256) {
      const u64* hp2 = hg + (long)((s + 1) & 1) * 2048 + prow * 256 + c32 * 2;
#pragma unroll
      for (int j = 0; j < 4; j++)
        if (!((ownm >> j) & 1)) {
          a[2 * j] = __hip_atomic_load(hp2 + j * 64, __ATOMIC_RELAXED, __HIP_MEMORY_SCOPE_AGENT);
          a[2 * j + 1] =
              __hip_atomic_load(hp2 + j * 64 + 1, __ATOMIC_RELAXED, __HIP_MEMORY_SCOPE_AGENT);
        }
    }
    __builtin_amdgcn_sched_barrier(0);  // keep nonlin/stores AFTER the issue
    gbuf[wave][nl][ml + 0] = acc[0];
    gbuf[wave][nl][ml + 1] = acc[1];
    gbuf[wave][nl][ml + 2] = acc[2];
    gbuf[wave][nl][ml + 3] = acc[3];
    if (lane < 32) {
      int ul = lane & 3, b = lane >> 2;
      float gi = gbuf[wave][ul * 4 + 0][b];
      float gf = gbuf[wave][ul * 4 + 1][b];
      float gg = gbuf[wave][ul * 4 + 2][b];
      float go = gbuf[wave][ul * 4 + 3][b];
      float c = c_s[wave][ul][b];
      c = sigm(gf) * c + sigm(gi) * tanh_(gg);
      float h = sigm(go) * tanh_(c);
      c_s[wave][ul][b] = c;
      int u = nt * 4 + ul;
      u16 hb2 = f2b16(h);
      u32 partner = (u32)__shfl_down((int)hb2, 1);
      if ((ul & 1) == 0) {
        u32 pair = (u32)hb2 | (partner << 16);
        *(u32*)&hcat[((long)b * 256 + t) * 1024 + dir * 512 + u] = pair;
        u64 word = (u64)pair | ((u64)(u32)(s + 1) << 32);
        __hip_atomic_store(hg + (long)((s + 1) & 1) * 2048 + b * 256 + (u >> 1), word,
                           __ATOMIC_RELAXED, __HIP_MEMORY_SCOPE_AGENT);
        // own-word fast path: straight into next step's LDS buffer
        ((u32*)&h_s[(s + 1) & 1][0])[b * 260 + (u >> 1)] = pair;
      }
    }
  }
}

// Decoder: 32 WGs, 1024 steps. hglob: u64[2][8][256]. dec_out bf16 [8,1024,512].
__global__ __launch_bounds__(256) void dec_rec_k(
    const float* __restrict__ xg, const u16* __restrict__ whh,
    u16* __restrict__ dec_out, u64* __restrict__ hglob) {
  int wg = blockIdx.x;
  int tid = threadIdx.x, wave = tid >> 6, lane = tid & 63;
  int nl = lane & 15, kb = (lane >> 4) * 8, ml = (lane >> 4) * 4;
  int nt = wg * 4 + wave;
  __shared__ u16 h_s[2][16 * 520];
  __shared__ float gbuf[4][16][17];
  __shared__ float c_s[4][4][8];
  short8 warr[16];
  {
    const u16* wr = whh + (long)(wg * 64 + wave * 16 + nl) * 512 + kb;
#pragma unroll
    for (int kc = 0; kc < 16; kc++) warr[kc] = *(const short8*)(wr + kc * 32);
  }
  if (lane < 32) c_s[wave][lane & 3][lane >> 2] = 0.f;
  __syncthreads();
  float nxt[4];
#pragma unroll
  for (int r = 0; r < 4; r++) {
    int m = ml + r;
    nxt[r] = (m < 8) ? xg[((long)m * 1024 + 0) * 2048 + nt * 16 + nl] : 0.f;
  }
  int prow = tid >> 5, c32 = tid & 31;
  u32 ownm = 0;
#pragma unroll
  for (int j = 0; j < 4; j++)
    if (((j * 64 + c32 * 2) >> 3) == wg) ownm |= 1u << j;
  u64 a[8];
  for (int s = 0; s < 1024; ++s) {
    int pb = s & 1;
    float cur0 = nxt[0], cur1 = nxt[1], cur2 = nxt[2], cur3 = nxt[3];
    if (s > 0) {  // finalize discovery: check speculative round, re-poll stale
      const u64* hp = hglob + (long)pb * 2048 + prow * 256 + c32 * 2;
      u32 tg = (u32)s;
      for (;;) {
        u32 bad = 0;
#pragma unroll
        for (int j = 0; j < 4; j++)
          if (!((ownm >> j) & 1))
            bad |= ((u32)(a[2 * j] >> 32) ^ tg) | ((u32)(a[2 * j + 1] >> 32) ^ tg);
        if (!bad) break;
#pragma unroll
        for (int j = 0; j < 4; j++)
          if (!((ownm >> j) & 1) &&
              ((((u32)(a[2 * j] >> 32)) ^ tg) | (((u32)(a[2 * j + 1] >> 32)) ^ tg))) {
            a[2 * j] = __hip_atomic_load(hp + j * 64, __ATOMIC_RELAXED, __HIP_MEMORY_SCOPE_AGENT);
            a[2 * j + 1] =
                __hip_atomic_load(hp + j * 64 + 1, __ATOMIC_RELAXED, __HIP_MEMORY_SCOPE_AGENT);
          }
      }
      u64* dp = (u64*)(h_s[pb] + prow * 520);
#pragma unroll
      for (int j = 0; j < 4; j++)
        if (!((ownm >> j) & 1))
          dp[c32 + j * 32] = (a[2 * j] & 0xffffffffull) | (a[2 * j + 1] << 32);
    }
    __builtin_amdgcn_sched_barrier(0);  // prefetch issue stays AFTER the check
    if (s + 1 < 1024) {
#pragma unroll
      for (int r = 0; r < 4; r++) {
        int m = ml + r;
        nxt[r] = (m < 8) ? xg[((long)m * 1024 + (s + 1)) * 2048 + nt * 16 + nl] : 0.f;
      }
    }
    __syncthreads();  // pack + own-LDS writes visible -> MFMA
    float4_ ac0, ac1, ac2, ac3;
    ac0[0] = cur0; ac0[1] = cur1; ac0[2] = cur2; ac0[3] = cur3;
    ac1[0] = 0; ac1[1] = 0; ac1[2] = 0; ac1[3] = 0;
    ac2 = ac1; ac3 = ac1;
    if (s > 0) {
      const u16* hrow = h_s[pb] + nl * 520 + kb;
#pragma unroll
      for (int kc = 0; kc < 16; kc += 4) {
        ac0 = __builtin_amdgcn_mfma_f32_16x16x32_bf16(
            *(const short8*)(hrow + (kc + 0) * 32), warr[kc + 0], ac0, 0, 0, 0);
        ac1 = __builtin_amdgcn_mfma_f32_16x16x32_bf16(
            *(const short8*)(hrow + (kc + 1) * 32), warr[kc + 1], ac1, 0, 0, 0);
        ac2 = __builtin_amdgcn_mfma_f32_16x16x32_bf16(
            *(const short8*)(hrow + (kc + 2) * 32), warr[kc + 2], ac2, 0, 0, 0);
        ac3 = __builtin_amdgcn_mfma_f32_16x16x32_bf16(
            *(const short8*)(hrow + (kc + 3) * 32), warr[kc + 3], ac3, 0, 0, 0);
      }
    }
    float4_ acc = (ac0 + ac1) + (ac2 + ac3);
    // speculative poll round for h(s+1): flies under nonlin+store+loop-top
    if (s + 1 < 1024) {
      const u64* hp2 = hglob + (long)((s + 1) & 1) * 2048 + prow * 256 + c32 * 2;
#pragma unroll
      for (int j = 0; j < 4; j++)
        if (!((ownm >> j) & 1)) {
          a[2 * j] = __hip_atomic_load(hp2 + j * 64, __ATOMIC_RELAXED, __HIP_MEMORY_SCOPE_AGENT);
          a[2 * j + 1] =
              __hip_atomic_load(hp2 + j * 64 + 1, __ATOMIC_RELAXED, __HIP_MEMORY_SCOPE_AGENT);
        }
    }
    __builtin_amdgcn_sched_barrier(0);  // keep nonlin/stores AFTER the issue
    gbuf[wave][nl][ml + 0] = acc[0];
    gbuf[wave][nl][ml + 1] = acc[1];
    gbuf[wave][nl][ml + 2] = acc[2];
    gbuf[wave][nl][ml + 3] = acc[3];
    if (lane < 32) {
      int ul = lane & 3, b = lane >> 2;
      float gi = gbuf[wave][ul * 4 + 0][b];
      float gf = gbuf[wave][ul * 4 + 1][b];
      float gg = gbuf[wave][ul * 4 + 2][b];
      float go = gbuf[wave][ul * 4 + 3][b];
      float c = c_s[wave][ul][b];
      c = sigm(gf) * c + sigm(gi) * tanh_(gg);
      float h = sigm(go) * tanh_(c);
      c_s[wave][ul][b] = c;
      int u = nt * 4 + ul;
      u16 hb2 = f2b16(h);
      u32 partner = (u32)__shfl_down((int)hb2, 1);
      if ((ul & 1) == 0) {
        u32 pair = (u32)hb2 | (partner << 16);
        *(u32*)&dec_out[((long)b * 1024 + s) * 512 + u] = pair;
        u64 word = (u64)pair | ((u64)(u32)(s + 1) << 32);
        __hip_atomic_store(hglob + (long)((s + 1) & 1) * 2048 + b * 256 + (u >> 1), word,
                           __ATOMIC_RELAXED, __HIP_MEMORY_SCOPE_AGENT);
        // own-word fast path: straight into next step's LDS buffer
        ((u32*)&h_s[(s + 1) & 1][0])[b * 260 + (u >> 1)] = pair;
      }
    }
  }
}

// ---------------- host ----------------
extern "C" void kernel_launch(void* const* d_in, const int* in_sizes, int n_in,
                              void* d_out, int out_size, void* d_ws, size_t ws_size,
                              hipStream_t stream) {
  (void)in_sizes; (void)n_in; (void)out_size; (void)ws_size;
  const int* pid = (const int*)d_in[0];
  const float* mel = (const float*)d_in[1];
  const float* dur = (const float*)d_in[2];
  const float* emb = (const float*)d_in[3];
  const float* e_ihf = (const float*)d_in[4];
  const float* e_hhf = (const float*)d_in[5];
  const float* e_bihf = (const float*)d_in[6];
  const float* e_bhhf = (const float*)d_in[7];
  const float* e_ihb = (const float*)d_in[8];
  const float* e_hhb = (const float*)d_in[9];
  const float* e_bihb = (const float*)d_in[10];
  const float* e_bhhb = (const float*)d_in[11];
  const float* proj_w = (const float*)d_in[12];
  const float* proj_b = (const float*)d_in[13];
  const float* dw1 = (const float*)d_in[14];
  const float* db1 = (const float*)d_in[15];
  const float* dw2 = (const float*)d_in[16];
  const float* db2 = (const float*)d_in[17];
  const float* dw3 = (const float*)d_in[18];
  const float* db3 = (const float*)d_in[19];
  const float* miw = (const float*)d_in[20];
  const float* mib = (const float*)d_in[21];
  const float* aiw = (const float*)d_in[22];
  const float* aib = (const float*)d_in[23];
  const float* aow = (const float*)d_in[24];
  const float* aob = (const float*)d_in[25];
  const float* d_ih = (const float*)d_in[26];
  const float* d_hh = (const float*)d_in[27];
  const float* d_bih = (const float*)d_in[28];
  const float* d_bhh = (const float*)d_in[29];
  const float* mow = (const float*)d_in[30];
  const float* mob = (const float*)d_in[31];
  float* out = (float*)d_out;

  char* W = (char*)d_ws;
  // ---- workspace layout (bytes); overlays noted ----
  constexpr size_t o_xgf = 0;                        // f32 [2048,2048]   16 MB
  constexpr size_t o_xgb = o_xgf + 16777216;         // f32               16 MB
  constexpr size_t o_sbuf = o_xgb + 16777216;        // f32 [8,1024,1024] 32 MB
  constexpr size_t o_decxg = o_xgf;                  // overlay: f32 [8192,2048] 64 MB
  constexpr size_t o_pool = o_sbuf + 33554432;
  constexpr size_t o_x = o_pool;                     // bf16 [2048,512]    2 MB
  constexpr size_t o_hcat = o_x + 2097152;           // bf16 [2048,1024]   4 MB
  constexpr size_t o_dh1 = o_hcat + 4194304;         // bf16 [2048,512]    2 MB
  constexpr size_t o_dh2 = o_dh1 + 2097152;          // bf16 [2048,256]    1 MB
  constexpr size_t o_melin = o_dh2 + 1048576;        // bf16 [8192,128]    2 MB
  constexpr size_t o_att = o_pool;                   // overlay: bf16 [8192,512] 8 MB
  constexpr size_t o_enc = o_melin + 2097152;        // bf16 [2048,512]    2 MB
  constexpr size_t o_exp = o_enc + 2097152;          // bf16 [8192,512]    8 MB
  constexpr size_t o_ctx = o_exp;                    // overlay after k/v
  constexpr size_t o_qin = o_exp + 8388608;          // bf16 [8192,512]    8 MB
  constexpr size_t o_q = o_qin + 8388608;            // bf16 [8192,512]    8 MB
  constexpr size_t o_decout = o_q;                   // overlay after attention
  constexpr size_t o_k = o_q + 8388608;              // bf16 [8192,512]    8 MB
  constexpr size_t o_vt = o_k + 8388608;             // bf16 [8,512,1024]+pad
  constexpr size_t o_p = o_vt + 8519680;             // bf16 [8,1024,1024] 16 MB
  constexpr size_t o_w0 = o_p + 16777216;
  constexpr size_t o_w_eihf = o_w0;                  // bf16 [2048,512] perm
  constexpr size_t o_w_eihb = o_w_eihf + 2097152;
  constexpr size_t o_w_ehhf = o_w_eihb + 2097152;
  constexpr size_t o_w_ehhb = o_w_ehhf + 2097152;
  constexpr size_t o_w_dih = o_w_ehhb + 2097152;     // bf16 [2048,1024] perm
  constexpr size_t o_w_dhh = o_w_dih + 4194304;      // bf16 [2048,512] perm
  constexpr size_t o_w_proj = o_w_dhh + 2097152;     // bf16 [512,1024]
  constexpr size_t o_w_d1 = o_w_proj + 1048576;      // bf16 [512,512]
  constexpr size_t o_w_d2 = o_w_d1 + 524288;         // bf16 [256,512]
  constexpr size_t o_w_ai = o_w_d2 + 262144;         // bf16 [1536,512]
  constexpr size_t o_w_ao = o_w_ai + 1572864;        // bf16 [512,512]
  constexpr size_t o_w_mi = o_w_ao + 524288;         // bf16 [512,128]
  constexpr size_t o_w_mo = o_w_mi + 131072;         // bf16 [128,512]
  constexpr size_t o_bc_ef = o_w_mo + 131072;        // f32 [2048]
  constexpr size_t o_bc_eb = o_bc_ef + 8192;
  constexpr size_t o_bc_d = o_bc_eb + 8192;
  constexpr size_t o_b_mo = o_bc_d + 8192;           // f32 [128]
  constexpr size_t o_cum = o_b_mo + 512;             // int [8,256]
  constexpr size_t o_lb = o_cum + 8192;              // int [8]
  constexpr size_t o_hge = o_lb + 256;               // u64 [2dir][2][8][256] = 64 KB
  constexpr size_t o_hgd = o_hge + 65536;            // u64 [2][8][256]       = 32 KB

  // zero the tagged h buffers (tag 0 != any step >= 1)
  hipMemsetAsync(W + o_hge, 0, 98304, stream);

  // weight conversions
  f2b_k<<<512, 256, 0, stream>>>(proj_w, (u16*)(W + o_w_proj), 512 * 1024);
  f2b_k<<<512, 256, 0, stream>>>(dw1, (u16*)(W + o_w_d1), 512 * 512);
  f2b_k<<<256, 256, 0, stream>>>(dw2, (u16*)(W + o_w_d2), 256 * 512);
  f2b_k<<<512, 256, 0, stream>>>(aiw, (u16*)(W + o_w_ai), 1536 * 512);
  f2b_k<<<512, 256, 0, stream>>>(aow, (u16*)(W + o_w_ao), 512 * 512);
  permconv_k<<<2048, 256, 0, stream>>>(e_ihf, (u16*)(W + o_w_eihf), 512);
  permconv_k<<<2048, 256, 0, stream>>>(e_ihb, (u16*)(W + o_w_eihb), 512);
  permconv_k<<<2048, 256, 0, stream>>>(e_hhf, (u16*)(W + o_w_ehhf), 512);
  permconv_k<<<2048, 256, 0, stream>>>(e_hhb, (u16*)(W + o_w_ehhb), 512);
  permconv_k<<<2048, 256, 0, stream>>>(d_ih, (u16*)(W + o_w_dih), 1024);
  permconv_k<<<2048, 256, 0, stream>>>(d_hh, (u16*)(W + o_w_dhh), 512);
  biascomb_k<<<8, 256, 0, stream>>>(e_bihf, e_bhhf, (float*)(W + o_bc_ef));
  biascomb_k<<<8, 256, 0, stream>>>(e_bihb, e_bhhb, (float*)(W + o_bc_eb));
  biascomb_k<<<8, 256, 0, stream>>>(d_bih, d_bhh, (float*)(W + o_bc_d));
  melinw_k<<<512, 128, 0, stream>>>(miw, (u16*)(W + o_w_mi));
  meloutw_k<<<128, 256, 0, stream>>>(mow, (u16*)(W + o_w_mo));
  biaspad_k<<<1, 128, 0, stream>>>(mob, (float*)(W + o_b_mo));

  auto gemm = [&](size_t oA, size_t oA2, int ksplit, int lda, int lda2, long sA, size_t oB,
                  int ldb, long sB, void* C, int ldc, long sC, const float* bias, float alpha,
                  int M, int N, int K, int flags, int batch) {
    dim3 g(M / 128, (N + 127) / 128, batch);
    gemm_bt<<<g, 256, 0, stream>>>((const u16*)(W + oA),
                                   oA2 ? (const u16*)(W + oA2) : (const u16*)0, ksplit, lda, lda2,
                                   sA, (const u16*)(W + oB), ldb, sB, C, ldc, sC, bias, alpha, N,
                                   K, flags);
  };

  // encoder
  embed_k<<<dim3(256, 8), 256, 0, stream>>>(pid, emb, (u16*)(W + o_x));
  gemm(o_x, 0, 512, 512, 0, 0, o_w_eihf, 512, 0, W + o_xgf, 2048, 0,
       (const float*)(W + o_bc_ef), 1.f, 2048, 2048, 512, 0, 1);
  gemm(o_x, 0, 512, 512, 0, 0, o_w_eihb, 512, 0, W + o_xgb, 2048, 0,
       (const float*)(W + o_bc_eb), 1.f, 2048, 2048, 512, 0, 1);
  enc_rec_k<<<64, 256, 0, stream>>>((const float*)(W + o_xgf), (const float*)(W + o_xgb),
                                    (const u16*)(W + o_w_ehhf), (const u16*)(W + o_w_ehhb),
                                    (u16*)(W + o_hcat), (u64*)(W + o_hge));
  gemm(o_hcat, 0, 1024, 1024, 0, 0, o_w_proj, 1024, 0, W + o_enc, 512, 0, proj_b, 1.f, 2048, 512,
       1024, 1, 1);
  // duration predictor
  gemm(o_enc, 0, 512, 512, 0, 0, o_w_d1, 512, 0, W + o_dh1, 512, 0, db1, 1.f, 2048, 512, 512, 3, 1);
  gemm(o_dh1, 0, 512, 512, 0, 0, o_w_d2, 512, 0, W + o_dh2, 256, 0, db2, 1.f, 2048, 256, 512, 3, 1);
  dur3_k<<<512, 256, 0, stream>>>((const u16*)(W + o_dh2), dw3, db3, out + 655360);
  // length regulation
  cumsum_k<<<8, 256, 0, stream>>>(dur, (int*)(W + o_cum), (int*)(W + o_lb));
  gather_k<<<dim3(1024, 8), 256, 0, stream>>>((const int*)(W + o_cum), (const u16*)(W + o_enc),
                                              (u16*)(W + o_exp));
  // attention inputs
  melin_k<<<dim3(1024, 8), 128, 0, stream>>>(mel, (u16*)(W + o_melin));
  gemm(o_melin, 0, 128, 128, 0, 0, o_w_mi, 128, 0, W + o_qin, 512, 0, mib, 1.f, 8192, 512, 128, 1, 1);
  gemm(o_qin, 0, 512, 512, 0, 0, o_w_ai, 512, 0, W + o_q, 512, 0, aib, 1.f, 8192, 512, 512, 1, 1);
  gemm(o_exp, 0, 512, 512, 0, 0, o_w_ai + (size_t)512 * 512 * 2, 512, 0, W + o_k, 512, 0,
       aib + 512, 1.f, 8192, 512, 512, 1, 1);
  // v stored transposed per batch: v_t[b][d][t]
  gemm(o_exp, 0, 512, 512, 0, 524288, o_w_ai + (size_t)1024 * 512 * 2, 512, 0, W + o_vt, 1024,
       524288, aib + 1024, 1.f, 1024, 512, 512, 5, 8);
  // per-head attention
  for (int h = 0; h < 8; h++) {
    gemm(o_q + (size_t)h * 128, 0, 64, 512, 0, 524288, o_k + (size_t)h * 128, 512, 524288,
         W + o_sbuf, 1024, 1048576, (const float*)0, 0.125f, 1024, 1024, 64, 0, 8);
    softmax_k<<<dim3(1024, 8), 256, 0, stream>>>((const float*)(W + o_sbuf), (u16*)(W + o_p),
                                                 (const int*)(W + o_lb));
    gemm(o_p, 0, 1024, 1024, 0, 1048576, o_vt + (size_t)h * 64 * 1024 * 2, 1024, 524288,
         (u16*)(W + o_ctx) + h * 64, 512, 524288, (const float*)0, 1.f, 1024, 64, 1024, 1, 8);
  }
  gemm(o_ctx, 0, 512, 512, 0, 0, o_w_ao, 512, 0, W + o_att, 512, 0, aob, 1.f, 8192, 512, 512, 1, 1);
  // decoder
  gemm(o_qin, o_att, 512, 512, 512, 0, o_w_dih, 1024, 0, W + o_decxg, 2048, 0,
       (const float*)(W + o_bc_d), 1.f, 8192, 2048, 1024, 0, 1);
  dec_rec_k<<<32, 256, 0, stream>>>((const float*)(W + o_decxg), (const u16*)(W + o_w_dhh),
                                    (u16*)(W + o_decout), (u64*)(W + o_hgd));
  gemm(o_decout, 0, 512, 512, 0, 0, o_w_mo, 512, 0, d_out, 80, 0, (const float*)(W + o_b_mo), 1.f,
       8192, 80, 512, 0, 1);
}

// Round 9
// 3140.776 us; speedup vs baseline: 1.1439x; 1.1439x over previous
//
#include <hip/hip_runtime.h>
#include <hip/hip_bf16.h>

// Kokoro TTS forward, fused bf16-MFMA pipeline.
// B=8, T_TEXT=256, T_MEL=1024, H=512, MEL=80, NH=8, HD=64.
// All linears: one MFMA GEMM kernel (C = alpha*A@B^T + bias), A/B bf16, acc fp32.
// LSTM recurrences: persistent kernels (1 WG/CU). Tag-in-word dataflow at
// AGENT scope: each h-pair is one relaxed agent u64 {pair(lo32), step(hi32)};
// producers fire-and-forget; every compute thread polls its own 8 words,
// packs to LDS (conflict-free dense slots), one __syncthreads, MFMA with
// W_hh in VGPRs (R7: 1800us dec). R8's speculative pre-poll sampled before
// producers stored -- always missed, pure overhead (-350us): reverted.
// R9: PREFETCH MOVED PAST THE BARRIER. __syncthreads lowers to
// s_waitcnt vmcnt(0)+s_barrier for EVERY wave (R4 lesson). R3-R8 issued the
// xg HBM prefetch immediately BEFORE the barrier, so every step every wave
// drained a fresh ~600-900cy HBM load at the barrier -- the missing ~1500cy
// in R7's 4220cy/step ledger. Now the prefetch issues right AFTER the
// barrier (loads cannot hoist across a barrier), flying under MFMA + nonlin
// + next step's poll (~2000cy) before its use at the next step's seed. The
// barrier now drains only already-complete poll loads and ~700cy-old store
// acks.
// Gate rows permuted rho(G,u)=4u+G so each 16-wide n-tile = 4 units x 4 gates.

typedef unsigned short u16;
typedef unsigned int u32;
typedef unsigned long long u64;
typedef short short8 __attribute__((ext_vector_type(8)));
typedef float float4_ __attribute__((ext_vector_type(4)));

__device__ __forceinline__ u16 f2b16(float f) {
  u32 u = __float_as_uint(f);
  u = (u + 0x7FFF + ((u >> 16) & 1)) >> 16;
  return (u16)u;
}
__device__ __forceinline__ float b2f(u16 h) { return __uint_as_float((u32)h << 16); }
__device__ __forceinline__ float sigm(float x) { return 1.f / (1.f + __expf(-x)); }
__device__ __forceinline__ float tanh_(float x) { return 2.f / (1.f + __expf(-2.f * x)) - 1.f; }

// ---------------- small conversion kernels ----------------
__global__ void f2b_k(const float* __restrict__ s, u16* __restrict__ d, int n) {
  for (int i = blockIdx.x * 256 + threadIdx.x; i < n; i += gridDim.x * 256) d[i] = f2b16(s[i]);
}
// LSTM weight rows [2048,K]: out row r=4u+G <- src row G*512+u, f32->bf16
__global__ void permconv_k(const float* __restrict__ s, u16* __restrict__ d, int K) {
  int row = blockIdx.x; int u = row >> 2, G = row & 3;
  const float* sr = s + (long)(G * 512 + u) * K;
  u16* dr = d + (long)row * K;
  for (int c = threadIdx.x; c < K; c += 256) dr[c] = f2b16(sr[c]);
}
__global__ void biascomb_k(const float* __restrict__ bih, const float* __restrict__ bhh,
                           float* __restrict__ out) {
  int r = blockIdx.x * 256 + threadIdx.x; // 2048
  int u = r >> 2, G = r & 3;
  out[r] = bih[G * 512 + u] + bhh[G * 512 + u];
}
// mel_in_w [512,80] -> [512,128] zero-padded bf16
__global__ void melinw_k(const float* __restrict__ s, u16* __restrict__ d) {
  int row = blockIdx.x, c = threadIdx.x; // block 128
  d[row * 128 + c] = (c < 80) ? f2b16(s[row * 80 + c]) : (u16)0;
}
// mel_out_w [80,512] -> [128,512] zero row-padded bf16
__global__ void meloutw_k(const float* __restrict__ s, u16* __restrict__ d) {
  int row = blockIdx.x;
  for (int c = threadIdx.x; c < 512; c += 256)
    d[row * 512 + c] = (row < 80) ? f2b16(s[row * 512 + c]) : (u16)0;
}
__global__ void biaspad_k(const float* __restrict__ s, float* __restrict__ d) {
  int t = threadIdx.x; // 128
  d[t] = (t < 80) ? s[t] : 0.f;
}
// embedding gather -> bf16 [8,256,512]
__global__ void embed_k(const int* __restrict__ pid, const float* __restrict__ emb,
                        u16* __restrict__ x) {
  int t = blockIdx.x, b = blockIdx.y;
  int row = pid[b * 256 + t];
  const float* e = emb + (long)row * 512;
  u16* xr = x + ((long)b * 256 + t) * 512;
  xr[threadIdx.x] = f2b16(e[threadIdx.x]);
  xr[threadIdx.x + 256] = f2b16(e[threadIdx.x + 256]);
}
// mel shift + pad K 80->128 -> bf16 [8,1024,128]
__global__ void melin_k(const float* __restrict__ mel, u16* __restrict__ out) {
  int t = blockIdx.x, b = blockIdx.y, c = threadIdx.x; // block 128
  float v = (c < 80 && t > 0) ? mel[((long)b * 1024 + (t - 1)) * 80 + c] : 0.f;
  out[((long)b * 1024 + t) * 128 + c] = f2b16(v);
}
// per-batch duration cumsum (values are exact small ints)
__global__ void cumsum_k(const float* __restrict__ dur, int* __restrict__ cum,
                         int* __restrict__ Lb) {
  int b = blockIdx.x, t = threadIdx.x;
  __shared__ int sd[256];
  sd[t] = __float2int_rn(dur[b * 256 + t]);
  __syncthreads();
  for (int o = 1; o < 256; o <<= 1) {
    int v = (t >= o) ? sd[t - o] : 0;
    __syncthreads();
    sd[t] += v;
    __syncthreads();
  }
  cum[b * 256 + t] = sd[t];
  if (t == 255) Lb[b] = min(sd[255], 1024);
}
// length-regulate gather: exp[b,pos,:] = pad ? 0 : enc[b,idx,:]
__global__ void gather_k(const int* __restrict__ cum, const u16* __restrict__ enc,
                         u16* __restrict__ exp_) {
  int pos = blockIdx.x, b = blockIdx.y;
  const int* cb = cum + b * 256;
  int last = cb[255];
  u32 val = 0;
  if (pos < last) {
    int lo = 0, hi = 255;
    while (lo < hi) { int mid = (lo + hi) >> 1; if (cb[mid] > pos) hi = mid; else lo = mid + 1; }
    val = ((const u32*)(enc + ((long)b * 256 + lo) * 512))[threadIdx.x];
  }
  ((u32*)(exp_ + ((long)b * 1024 + pos) * 512))[threadIdx.x] = val;
}
// row softmax over [0,L) with bf16 P output (zeros beyond L)
__global__ void softmax_k(const float* __restrict__ sbuf, u16* __restrict__ P,
                          const int* __restrict__ Lb) {
  int qp = blockIdx.x, b = blockIdx.y;
  const float* s = sbuf + ((long)b * 1024 + qp) * 1024;
  u16* p = P + ((long)b * 1024 + qp) * 1024;
  int L = Lb[b];
  __shared__ float red[256];
  int tid = threadIdx.x;
  float m = -1e30f;
  for (int i = tid; i < L; i += 256) m = fmaxf(m, s[i]);
  red[tid] = m; __syncthreads();
  for (int o = 128; o > 0; o >>= 1) { if (tid < o) red[tid] = fmaxf(red[tid], red[tid + o]); __syncthreads(); }
  float mx = red[0];
  __syncthreads();
  float sm = 0.f;
  for (int i = tid; i < L; i += 256) sm += __expf(s[i] - mx);
  red[tid] = sm; __syncthreads();
  for (int o = 128; o > 0; o >>= 1) { if (tid < o) red[tid] += red[tid + o]; __syncthreads(); }
  float inv = 1.f / red[0];
  for (int i = tid; i < 1024; i += 256) {
    float v = (i < L) ? __expf(s[i] - mx) * inv : 0.f;
    p[i] = f2b16(v);
  }
}
// log_dur = h2 @ w3^T + b3  (K=256, N=1), fp32
__global__ void dur3_k(const u16* __restrict__ h2, const float* __restrict__ w3,
                       const float* __restrict__ b3, float* __restrict__ out) {
  int row = blockIdx.x * 4 + (threadIdx.x >> 6);
  int l = threadIdx.x & 63;
  const u16* hr = h2 + (long)row * 256;
  float s = 0.f;
  for (int i = 0; i < 4; i++) { int c = l * 4 + i; s += b2f(hr[c]) * w3[c]; }
  for (int o = 32; o > 0; o >>= 1) s += __shfl_down(s, o);
  if (l == 0) out[row] = s + b3[0];
}

// ---------------- GEMM: C[M,N] = alpha * A[M,K] @ B[N,K]^T (+bias[n]) ----------------
// flags: 1 = store bf16, 2 = relu, 4 = transposed C store (addr = n*ldc + m)
// A split option: k < ksplit from A, else from A2 (for dec_in concat).
// tiles 128x128xBK64, 256 thr, 4 waves 2x2, each wave 4x4 of mfma 16x16x32 bf16.
__global__ __launch_bounds__(256) void gemm_bt(
    const u16* __restrict__ A, const u16* __restrict__ A2, int ksplit, int lda, int lda2, long sA,
    const u16* __restrict__ B, int ldb, long sB, void* __restrict__ Cv, int ldc, long sC,
    const float* __restrict__ bias, float alpha, int N, int K, int flags) {
  __shared__ u16 As[128 * 72];
  __shared__ u16 Bs[128 * 72];
  int z = blockIdx.z;
  const u16* Ab = A + (long)z * sA;
  const u16* A2b = A2 ? (A2 + (long)z * sA) : (const u16*)0;
  const u16* Bb = B + (long)z * sB;
  int m0 = blockIdx.x * 128, n0 = blockIdx.y * 128;
  int tid = threadIdx.x, wave = tid >> 6, lane = tid & 63;
  int wm = wave & 1, wn = wave >> 1;
  int nl = lane & 15, kb = (lane >> 4) * 8, ml = (lane >> 4) * 4;
  float4_ acc[4][4];
  for (int i = 0; i < 4; i++)
    for (int j = 0; j < 4; j++) { acc[i][j][0] = 0; acc[i][j][1] = 0; acc[i][j][2] = 0; acc[i][j][3] = 0; }
  int rr = tid >> 3, cc = (tid & 7) * 8;
  for (int k0 = 0; k0 < K; k0 += 64) {
    int gk = k0 + cc;
#pragma unroll
    for (int i = 0; i < 4; i++) {
      int row = rr + i * 32;
      const u16* sa = (gk < ksplit) ? (Ab + (long)(m0 + row) * lda + gk)
                                    : (A2b + (long)(m0 + row) * lda2 + (gk - ksplit));
      *(short8*)&As[row * 72 + cc] = *(const short8*)sa;
      *(short8*)&Bs[row * 72 + cc] = *(const short8*)(Bb + (long)(n0 + row) * ldb + gk);
    }
    __syncthreads();
#pragma unroll
    for (int kk = 0; kk < 64; kk += 32) {
      short8 af[4], bfr[4];
#pragma unroll
      for (int i = 0; i < 4; i++) af[i] = *(const short8*)&As[(wm * 64 + i * 16 + nl) * 72 + kk + kb];
#pragma unroll
      for (int i = 0; i < 4; i++) bfr[i] = *(const short8*)&Bs[(wn * 64 + i * 16 + nl) * 72 + kk + kb];
#pragma unroll
      for (int mi = 0; mi < 4; mi++)
#pragma unroll
        for (int ni = 0; ni < 4; ni++)
          acc[mi][ni] = __builtin_amdgcn_mfma_f32_16x16x32_bf16(af[mi], bfr[ni], acc[mi][ni], 0, 0, 0);
    }
    __syncthreads();
  }
  for (int ni = 0; ni < 4; ni++) {
    int n = n0 + wn * 64 + ni * 16 + nl;
    if (n >= N) continue;
    float bv = bias ? bias[n] : 0.f;
    for (int mi = 0; mi < 4; mi++) {
#pragma unroll
      for (int r = 0; r < 4; r++) {
        int m = m0 + wm * 64 + mi * 16 + ml + r;
        float v = acc[mi][ni][r] * alpha + bv;
        if (flags & 2) v = fmaxf(v, 0.f);
        long idx = (flags & 4) ? ((long)n * ldc + m) : ((long)m * ldc + n);
        if (flags & 1) ((u16*)Cv)[z * sC + idx] = f2b16(v);
        else ((float*)Cv)[z * sC + idx] = v;
      }
    }
  }
}

// ---------------- persistent LSTM recurrences ----------------
// Tagged-word dataflow: hglob is u64[2][8][256] per team, word = {pair, step}.
// Every compute thread polls its own 8 words (4 consecutive pairs), packs the
// payloads into h_s[pb] at dense 8B-stride slots (conflict-free), one
// __syncthreads, THEN the xg prefetch (post-barrier so the barrier's
// vmcnt(0) never drains it), then MFMA with W_hh held in VGPRs.

// Encoder: 64 WGs (dir = bid>>5), 256 steps. hglob: u64[dir][2][8][256].
__global__ __launch_bounds__(256) void enc_rec_k(
    const float* __restrict__ xg_f, const float* __restrict__ xg_b,
    const u16* __restrict__ whh_f, const u16* __restrict__ whh_b,
    u16* __restrict__ hcat, u64* __restrict__ hglob) {
  int dir = blockIdx.x >> 5, wg = blockIdx.x & 31;
  int tid = threadIdx.x, wave = tid >> 6, lane = tid & 63;
  int nl = lane & 15, kb = (lane >> 4) * 8, ml = (lane >> 4) * 4;
  int nt = wg * 4 + wave;
  const float* xg = dir ? xg_b : xg_f;
  const u16* whh = dir ? whh_b : whh_f;
  u64* hg = hglob + dir * 4096;
  __shared__ u16 h_s[2][16 * 520];
  __shared__ float gbuf[4][16][17];
  __shared__ float c_s[4][4][8];
  short8 warr[16];
  {
    const u16* wr = whh + (long)(wg * 64 + wave * 16 + nl) * 512 + kb;
#pragma unroll
    for (int kc = 0; kc < 16; kc++) warr[kc] = *(const short8*)(wr + kc * 32);
  }
  if (lane < 32) c_s[wave][lane & 3][lane >> 2] = 0.f;
  __syncthreads();
  float nxt[4];
  {
    int t0 = dir ? 255 : 0;
#pragma unroll
    for (int r = 0; r < 4; r++) {
      int m = ml + r;
      nxt[r] = (m < 8) ? xg[((long)m * 256 + t0) * 2048 + nt * 16 + nl] : 0.f;
    }
  }
  int prow = tid >> 5, c32 = tid & 31;
  for (int s = 0; s < 256; ++s) {
    int t = dir ? 255 - s : s;
    int pb = s & 1;
    // capture THIS step's xg before the prefetch overwrites nxt
    float cur0 = nxt[0], cur1 = nxt[1], cur2 = nxt[2], cur3 = nxt[3];
    if (s > 0) {  // poll h(s); only stale (landed) vmem is outstanding here
      const u64* hp = hg + (long)pb * 2048 + prow * 256 + c32 * 2;
      u64 a[8];
      u32 tg = (u32)s;
      for (;;) {
#pragma unroll
        for (int j = 0; j < 4; j++) {
          a[2 * j] = __hip_atomic_load(hp + j * 64, __ATOMIC_RELAXED, __HIP_MEMORY_SCOPE_AGENT);
          a[2 * j + 1] =
              __hip_atomic_load(hp + j * 64 + 1, __ATOMIC_RELAXED, __HIP_MEMORY_SCOPE_AGENT);
        }
        u32 bad = 0;
#pragma unroll
        for (int i = 0; i < 8; i++) bad |= ((u32)(a[i] >> 32) ^ tg);
        if (!bad) break;
      }
      // conflict-free pack: slots c32 + j*32 -> dense 8B stride across lanes
      u64* dp = (u64*)(h_s[pb] + prow * 520);
#pragma unroll
      for (int j = 0; j < 4; j++)
        dp[c32 + j * 32] = (a[2 * j] & 0xffffffffull) | (a[2 * j + 1] << 32);
    }
    __syncthreads();  // drains only complete loads/old store acks -- no fresh HBM
    // xg prefetch AFTER the barrier: flies under MFMA+nonlin+next poll (~2000cy)
    if (s + 1 < 256) {
      int tn = dir ? 255 - (s + 1) : (s + 1);
#pragma unroll
      for (int r = 0; r < 4; r++) {
        int m = ml + r;
        nxt[r] = (m < 8) ? xg[((long)m * 256 + tn) * 2048 + nt * 16 + nl] : 0.f;
      }
    }
    float4_ ac0, ac1, ac2, ac3;
    ac0[0] = cur0; ac0[1] = cur1; ac0[2] = cur2; ac0[3] = cur3;
    ac1[0] = 0; ac1[1] = 0; ac1[2] = 0; ac1[3] = 0;
    ac2 = ac1; ac3 = ac1;
    if (s > 0) {
      const u16* hrow = h_s[pb] + nl * 520 + kb;
#pragma unroll
      for (int kc = 0; kc < 16; kc += 4) {
        ac0 = __builtin_amdgcn_mfma_f32_16x16x32_bf16(
            *(const short8*)(hrow + (kc + 0) * 32), warr[kc + 0], ac0, 0, 0, 0);
        ac1 = __builtin_amdgcn_mfma_f32_16x16x32_bf16(
            *(const short8*)(hrow + (kc + 1) * 32), warr[kc + 1], ac1, 0, 0, 0);
        ac2 = __builtin_amdgcn_mfma_f32_16x16x32_bf16(
            *(const short8*)(hrow + (kc + 2) * 32), warr[kc + 2], ac2, 0, 0, 0);
        ac3 = __builtin_amdgcn_mfma_f32_16x16x32_bf16(
            *(const short8*)(hrow + (kc + 3) * 32), warr[kc + 3], ac3, 0, 0, 0);
      }
    }
    float4_ acc = (ac0 + ac1) + (ac2 + ac3);
    // gbuf + c_s are wave-local: same-wave DS ordering suffices, no barrier
    gbuf[wave][nl][ml + 0] = acc[0];
    gbuf[wave][nl][ml + 1] = acc[1];
    gbuf[wave][nl][ml + 2] = acc[2];
    gbuf[wave][nl][ml + 3] = acc[3];
    if (lane < 32) {
      int ul = lane & 3, b = lane >> 2;
      float gi = gbuf[wave][ul * 4 + 0][b];
      float gf = gbuf[wave][ul * 4 + 1][b];
      float gg = gbuf[wave][ul * 4 + 2][b];
      float go = gbuf[wave][ul * 4 + 3][b];
      float c = c_s[wave][ul][b];
      c = sigm(gf) * c + sigm(gi) * tanh_(gg);
      float h = sigm(go) * tanh_(c);
      c_s[wave][ul][b] = c;
      int u = nt * 4 + ul;
      u16 hb2 = f2b16(h);
      u32 partner = (u32)__shfl_down((int)hb2, 1);
      if ((ul & 1) == 0) {
        u32 pair = (u32)hb2 | (partner << 16);
        *(u32*)&hcat[((long)b * 256 + t) * 1024 + dir * 512 + u] = pair;
        u64 word = (u64)pair | ((u64)(u32)(s + 1) << 32);
        __hip_atomic_store(hg + (long)((s + 1) & 1) * 2048 + b * 256 + (u >> 1), word,
                           __ATOMIC_RELAXED, __HIP_MEMORY_SCOPE_AGENT);
      }
    }
  }
}

// Decoder: 32 WGs, 1024 steps. hglob: u64[2][8][256]. dec_out bf16 [8,1024,512].
__global__ __launch_bounds__(256) void dec_rec_k(
    const float* __restrict__ xg, const u16* __restrict__ whh,
    u16* __restrict__ dec_out, u64* __restrict__ hglob) {
  int wg = blockIdx.x;
  int tid = threadIdx.x, wave = tid >> 6, lane = tid & 63;
  int nl = lane & 15, kb = (lane >> 4) * 8, ml = (lane >> 4) * 4;
  int nt = wg * 4 + wave;
  __shared__ u16 h_s[2][16 * 520];
  __shared__ float gbuf[4][16][17];
  __shared__ float c_s[4][4][8];
  short8 warr[16];
  {
    const u16* wr = whh + (long)(wg * 64 + wave * 16 + nl) * 512 + kb;
#pragma unroll
    for (int kc = 0; kc < 16; kc++) warr[kc] = *(const short8*)(wr + kc * 32);
  }
  if (lane < 32) c_s[wave][lane & 3][lane >> 2] = 0.f;
  __syncthreads();
  float nxt[4];
#pragma unroll
  for (int r = 0; r < 4; r++) {
    int m = ml + r;
    nxt[r] = (m < 8) ? xg[((long)m * 1024 + 0) * 2048 + nt * 16 + nl] : 0.f;
  }
  int prow = tid >> 5, c32 = tid & 31;
  for (int s = 0; s < 1024; ++s) {
    int pb = s & 1;
    // capture THIS step's xg before the prefetch overwrites nxt
    float cur0 = nxt[0], cur1 = nxt[1], cur2 = nxt[2], cur3 = nxt[3];
    if (s > 0) {  // poll h(s) first: clean vmcnt, no fresh HBM load to drain
      const u64* hp = hglob + (long)pb * 2048 + prow * 256 + c32 * 2;
      u64 a[8];
      u32 tg = (u32)s;
      for (;;) {
#pragma unroll
        for (int j = 0; j < 4; j++) {
          a[2 * j] = __hip_atomic_load(hp + j * 64, __ATOMIC_RELAXED, __HIP_MEMORY_SCOPE_AGENT);
          a[2 * j + 1] =
              __hip_atomic_load(hp + j * 64 + 1, __ATOMIC_RELAXED, __HIP_MEMORY_SCOPE_AGENT);
        }
        u32 bad = 0;
#pragma unroll
        for (int i = 0; i < 8; i++) bad |= ((u32)(a[i] >> 32) ^ tg);
        if (!bad) break;
      }
      u64* dp = (u64*)(h_s[pb] + prow * 520);
#pragma unroll
      for (int j = 0; j < 4; j++)
        dp[c32 + j * 32] = (a[2 * j] & 0xffffffffull) | (a[2 * j + 1] << 32);
    }
    __syncthreads();  // drains only complete loads/old store acks -- no fresh HBM
    // xg prefetch AFTER the barrier: flies under MFMA+nonlin+next poll (~2000cy)
    if (s + 1 < 1024) {
#pragma unroll
      for (int r = 0; r < 4; r++) {
        int m = ml + r;
        nxt[r] = (m < 8) ? xg[((long)m * 1024 + (s + 1)) * 2048 + nt * 16 + nl] : 0.f;
      }
    }
    float4_ ac0, ac1, ac2, ac3;
    ac0[0] = cur0; ac0[1] = cur1; ac0[2] = cur2; ac0[3] = cur3;
    ac1[0] = 0; ac1[1] = 0; ac1[2] = 0; ac1[3] = 0;
    ac2 = ac1; ac3 = ac1;
    if (s > 0) {
      const u16* hrow = h_s[pb] + nl * 520 + kb;
#pragma unroll
      for (int kc = 0; kc < 16; kc += 4) {
        ac0 = __builtin_amdgcn_mfma_f32_16x16x32_bf16(
            *(const short8*)(hrow + (kc + 0) * 32), warr[kc + 0], ac0, 0, 0, 0);
        ac1 = __builtin_amdgcn_mfma_f32_16x16x32_bf16(
            *(const short8*)(hrow + (kc + 1) * 32), warr[kc + 1], ac1, 0, 0, 0);
        ac2 = __builtin_amdgcn_mfma_f32_16x16x32_bf16(
            *(const short8*)(hrow + (kc + 2) * 32), warr[kc + 2], ac2, 0, 0, 0);
        ac3 = __builtin_amdgcn_mfma_f32_16x16x32_bf16(
            *(const short8*)(hrow + (kc + 3) * 32), warr[kc + 3], ac3, 0, 0, 0);
      }
    }
    float4_ acc = (ac0 + ac1) + (ac2 + ac3);
    gbuf[wave][nl][ml + 0] = acc[0];
    gbuf[wave][nl][ml + 1] = acc[1];
    gbuf[wave][nl][ml + 2] = acc[2];
    gbuf[wave][nl][ml + 3] = acc[3];
    if (lane < 32) {
      int ul = lane & 3, b = lane >> 2;
      float gi = gbuf[wave][ul * 4 + 0][b];
      float gf = gbuf[wave][ul * 4 + 1][b];
      float gg = gbuf[wave][ul * 4 + 2][b];
      float go = gbuf[wave][ul * 4 + 3][b];
      float c = c_s[wave][ul][b];
      c = sigm(gf) * c + sigm(gi) * tanh_(gg);
      float h = sigm(go) * tanh_(c);
      c_s[wave][ul][b] = c;
      int u = nt * 4 + ul;
      u16 hb2 = f2b16(h);
      u32 partner = (u32)__shfl_down((int)hb2, 1);
      if ((ul & 1) == 0) {
        u32 pair = (u32)hb2 | (partner << 16);
        *(u32*)&dec_out[((long)b * 1024 + s) * 512 + u] = pair;
        u64 word = (u64)pair | ((u64)(u32)(s + 1) << 32);
        __hip_atomic_store(hglob + (long)((s + 1) & 1) * 2048 + b * 256 + (u >> 1), word,
                           __ATOMIC_RELAXED, __HIP_MEMORY_SCOPE_AGENT);
      }
    }
  }
}

// ---------------- host ----------------
extern "C" void kernel_launch(void* const* d_in, const int* in_sizes, int n_in,
                              void* d_out, int out_size, void* d_ws, size_t ws_size,
                              hipStream_t stream) {
  (void)in_sizes; (void)n_in; (void)out_size; (void)ws_size;
  const int* pid = (const int*)d_in[0];
  const float* mel = (const float*)d_in[1];
  const float* dur = (const float*)d_in[2];
  const float* emb = (const float*)d_in[3];
  const float* e_ihf = (const float*)d_in[4];
  const float* e_hhf = (const float*)d_in[5];
  const float* e_bihf = (const float*)d_in[6];
  const float* e_bhhf = (const float*)d_in[7];
  const float* e_ihb = (const float*)d_in[8];
  const float* e_hhb = (const float*)d_in[9];
  const float* e_bihb = (const float*)d_in[10];
  const float* e_bhhb = (const float*)d_in[11];
  const float* proj_w = (const float*)d_in[12];
  const float* proj_b = (const float*)d_in[13];
  const float* dw1 = (const float*)d_in[14];
  const float* db1 = (const float*)d_in[15];
  const float* dw2 = (const float*)d_in[16];
  const float* db2 = (const float*)d_in[17];
  const float* dw3 = (const float*)d_in[18];
  const float* db3 = (const float*)d_in[19];
  const float* miw = (const float*)d_in[20];
  const float* mib = (const float*)d_in[21];
  const float* aiw = (const float*)d_in[22];
  const float* aib = (const float*)d_in[23];
  const float* aow = (const float*)d_in[24];
  const float* aob = (const float*)d_in[25];
  const float* d_ih = (const float*)d_in[26];
  const float* d_hh = (const float*)d_in[27];
  const float* d_bih = (const float*)d_in[28];
  const float* d_bhh = (const float*)d_in[29];
  const float* mow = (const float*)d_in[30];
  const float* mob = (const float*)d_in[31];
  float* out = (float*)d_out;

  char* W = (char*)d_ws;
  // ---- workspace layout (bytes); overlays noted ----
  constexpr size_t o_xgf = 0;                        // f32 [2048,2048]   16 MB
  constexpr size_t o_xgb = o_xgf + 16777216;         // f32               16 MB
  constexpr size_t o_sbuf = o_xgb + 16777216;        // f32 [8,1024,1024] 32 MB
  constexpr size_t o_decxg = o_xgf;                  // overlay: f32 [8192,2048] 64 MB
  constexpr size_t o_pool = o_sbuf + 33554432;
  constexpr size_t o_x = o_pool;                     // bf16 [2048,512]    2 MB
  constexpr size_t o_hcat = o_x + 2097152;           // bf16 [2048,1024]   4 MB
  constexpr size_t o_dh1 = o_hcat + 4194304;         // bf16 [2048,512]    2 MB
  constexpr size_t o_dh2 = o_dh1 + 2097152;          // bf16 [2048,256]    1 MB
  constexpr size_t o_melin = o_dh2 + 1048576;        // bf16 [8192,128]    2 MB
  constexpr size_t o_att = o_pool;                   // overlay: bf16 [8192,512] 8 MB
  constexpr size_t o_enc = o_melin + 2097152;        // bf16 [2048,512]    2 MB
  constexpr size_t o_exp = o_enc + 2097152;          // bf16 [8192,512]    8 MB
  constexpr size_t o_ctx = o_exp;                    // overlay after k/v
  constexpr size_t o_qin = o_exp + 8388608;          // bf16 [8192,512]    8 MB
  constexpr size_t o_q = o_qin + 8388608;            // bf16 [8192,512]    8 MB
  constexpr size_t o_decout = o_q;                   // overlay after attention
  constexpr size_t o_k = o_q + 8388608;              // bf16 [8192,512]    8 MB
  constexpr size_t o_vt = o_k + 8388608;             // bf16 [8,512,1024]+pad
  constexpr size_t o_p = o_vt + 8519680;             // bf16 [8,1024,1024] 16 MB
  constexpr size_t o_w0 = o_p + 16777216;
  constexpr size_t o_w_eihf = o_w0;                  // bf16 [2048,512] perm
  constexpr size_t o_w_eihb = o_w_eihf + 2097152;
  constexpr size_t o_w_ehhf = o_w_eihb + 2097152;
  constexpr size_t o_w_ehhb = o_w_ehhf + 2097152;
  constexpr size_t o_w_dih = o_w_ehhb + 2097152;     // bf16 [2048,1024] perm
  constexpr size_t o_w_dhh = o_w_dih + 4194304;      // bf16 [2048,512] perm
  constexpr size_t o_w_proj = o_w_dhh + 2097152;     // bf16 [512,1024]
  constexpr size_t o_w_d1 = o_w_proj + 1048576;      // bf16 [512,512]
  constexpr size_t o_w_d2 = o_w_d1 + 524288;         // bf16 [256,512]
  constexpr size_t o_w_ai = o_w_d2 + 262144;         // bf16 [1536,512]
  constexpr size_t o_w_ao = o_w_ai + 1572864;        // bf16 [512,512]
  constexpr size_t o_w_mi = o_w_ao + 524288;         // bf16 [512,128]
  constexpr size_t o_w_mo = o_w_mi + 131072;         // bf16 [128,512]
  constexpr size_t o_bc_ef = o_w_mo + 131072;        // f32 [2048]
  constexpr size_t o_bc_eb = o_bc_ef + 8192;
  constexpr size_t o_bc_d = o_bc_eb + 8192;
  constexpr size_t o_b_mo = o_bc_d + 8192;           // f32 [128]
  constexpr size_t o_cum = o_b_mo + 512;             // int [8,256]
  constexpr size_t o_lb = o_cum + 8192;              // int [8]
  constexpr size_t o_hge = o_lb + 256;               // u64 [2dir][2][8][256] = 64 KB
  constexpr size_t o_hgd = o_hge + 65536;            // u64 [2][8][256]       = 32 KB

  // zero the tagged h buffers (tag 0 != any step >= 1)
  hipMemsetAsync(W + o_hge, 0, 98304, stream);

  // weight conversions
  f2b_k<<<512, 256, 0, stream>>>(proj_w, (u16*)(W + o_w_proj), 512 * 1024);
  f2b_k<<<512, 256, 0, stream>>>(dw1, (u16*)(W + o_w_d1), 512 * 512);
  f2b_k<<<256, 256, 0, stream>>>(dw2, (u16*)(W + o_w_d2), 256 * 512);
  f2b_k<<<512, 256, 0, stream>>>(aiw, (u16*)(W + o_w_ai), 1536 * 512);
  f2b_k<<<512, 256, 0, stream>>>(aow, (u16*)(W + o_w_ao), 512 * 512);
  permconv_k<<<2048, 256, 0, stream>>>(e_ihf, (u16*)(W + o_w_eihf), 512);
  permconv_k<<<2048, 256, 0, stream>>>(e_ihb, (u16*)(W + o_w_eihb), 512);
  permconv_k<<<2048, 256, 0, stream>>>(e_hhf, (u16*)(W + o_w_ehhf), 512);
  permconv_k<<<2048, 256, 0, stream>>>(e_hhb, (u16*)(W + o_w_ehhb), 512);
  permconv_k<<<2048, 256, 0, stream>>>(d_ih, (u16*)(W + o_w_dih), 1024);
  permconv_k<<<2048, 256, 0, stream>>>(d_hh, (u16*)(W + o_w_dhh), 512);
  biascomb_k<<<8, 256, 0, stream>>>(e_bihf, e_bhhf, (float*)(W + o_bc_ef));
  biascomb_k<<<8, 256, 0, stream>>>(e_bihb, e_bhhb, (float*)(W + o_bc_eb));
  biascomb_k<<<8, 256, 0, stream>>>(d_bih, d_bhh, (float*)(W + o_bc_d));
  melinw_k<<<512, 128, 0, stream>>>(miw, (u16*)(W + o_w_mi));
  meloutw_k<<<128, 256, 0, stream>>>(mow, (u16*)(W + o_w_mo));
  biaspad_k<<<1, 128, 0, stream>>>(mob, (float*)(W + o_b_mo));

  auto gemm = [&](size_t oA, size_t oA2, int ksplit, int lda, int lda2, long sA, size_t oB,
                  int ldb, long sB, void* C, int ldc, long sC, const float* bias, float alpha,
                  int M, int N, int K, int flags, int batch) {
    dim3 g(M / 128, (N + 127) / 128, batch);
    gemm_bt<<<g, 256, 0, stream>>>((const u16*)(W + oA),
                                   oA2 ? (const u16*)(W + oA2) : (const u16*)0, ksplit, lda, lda2,
                                   sA, (const u16*)(W + oB), ldb, sB, C, ldc, sC, bias, alpha, N,
                                   K, flags);
  };

  // encoder
  embed_k<<<dim3(256, 8), 256, 0, stream>>>(pid, emb, (u16*)(W + o_x));
  gemm(o_x, 0, 512, 512, 0, 0, o_w_eihf, 512, 0, W + o_xgf, 2048, 0,
       (const float*)(W + o_bc_ef), 1.f, 2048, 2048, 512, 0, 1);
  gemm(o_x, 0, 512, 512, 0, 0, o_w_eihb, 512, 0, W + o_xgb, 2048, 0,
       (const float*)(W + o_bc_eb), 1.f, 2048, 2048, 512, 0, 1);
  enc_rec_k<<<64, 256, 0, stream>>>((const float*)(W + o_xgf), (const float*)(W + o_xgb),
                                    (const u16*)(W + o_w_ehhf), (const u16*)(W + o_w_ehhb),
                                    (u16*)(W + o_hcat), (u64*)(W + o_hge));
  gemm(o_hcat, 0, 1024, 1024, 0, 0, o_w_proj, 1024, 0, W + o_enc, 512, 0, proj_b, 1.f, 2048, 512,
       1024, 1, 1);
  // duration predictor
  gemm(o_enc, 0, 512, 512, 0, 0, o_w_d1, 512, 0, W + o_dh1, 512, 0, db1, 1.f, 2048, 512, 512, 3, 1);
  gemm(o_dh1, 0, 512, 512, 0, 0, o_w_d2, 512, 0, W + o_dh2, 256, 0, db2, 1.f, 2048, 256, 512, 3, 1);
  dur3_k<<<512, 256, 0, stream>>>((const u16*)(W + o_dh2), dw3, db3, out + 655360);
  // length regulation
  cumsum_k<<<8, 256, 0, stream>>>(dur, (int*)(W + o_cum), (int*)(W + o_lb));
  gather_k<<<dim3(1024, 8), 256, 0, stream>>>((const int*)(W + o_cum), (const u16*)(W + o_enc),
                                              (u16*)(W + o_exp));
  // attention inputs
  melin_k<<<dim3(1024, 8), 128, 0, stream>>>(mel, (u16*)(W + o_melin));
  gemm(o_melin, 0, 128, 128, 0, 0, o_w_mi, 128, 0, W + o_qin, 512, 0, mib, 1.f, 8192, 512, 128, 1, 1);
  gemm(o_qin, 0, 512, 512, 0, 0, o_w_ai, 512, 0, W + o_q, 512, 0, aib, 1.f, 8192, 512, 512, 1, 1);
  gemm(o_exp, 0, 512, 512, 0, 0, o_w_ai + (size_t)512 * 512 * 2, 512, 0, W + o_k, 512, 0,
       aib + 512, 1.f, 8192, 512, 512, 1, 1);
  // v stored transposed per batch: v_t[b][d][t]
  gemm(o_exp, 0, 512, 512, 0, 524288, o_w_ai + (size_t)1024 * 512 * 2, 512, 0, W + o_vt, 1024,
       524288, aib + 1024, 1.f, 1024, 512, 512, 5, 8);
  // per-head attention
  for (int h = 0; h < 8; h++) {
    gemm(o_q + (size_t)h * 128, 0, 64, 512, 0, 524288, o_k + (size_t)h * 128, 512, 524288,
         W + o_sbuf, 1024, 1048576, (const float*)0, 0.125f, 1024, 1024, 64, 0, 8);
    softmax_k<<<dim3(1024, 8), 256, 0, stream>>>((const float*)(W + o_sbuf), (u16*)(W + o_p),
                                                 (const int*)(W + o_lb));
    gemm(o_p, 0, 1024, 1024, 0, 1048576, o_vt + (size_t)h * 64 * 1024 * 2, 1024, 524288,
         (u16*)(W + o_ctx) + h * 64, 512, 524288, (const float*)0, 1.f, 1024, 64, 1024, 1, 8);
  }
  gemm(o_ctx, 0, 512, 512, 0, 0, o_w_ao, 512, 0, W + o_att, 512, 0, aob, 1.f, 8192, 512, 512, 1, 1);
  // decoder
  gemm(o_qin, o_att, 512, 512, 512, 0, o_w_dih, 1024, 0, W + o_decxg, 2048, 0,
       (const float*)(W + o_bc_d), 1.f, 8192, 2048, 1024, 0, 1);
  dec_rec_k<<<32, 256, 0, stream>>>((const float*)(W + o_decxg), (const u16*)(W + o_w_dhh),
                                    (u16*)(W + o_decout), (u64*)(W + o_hgd));
  gemm(o_decout, 0, 512, 512, 0, 0, o_w_mo, 512, 0, d_out, 80, 0, (const float*)(W + o_b_mo), 1.f,
       8192, 80, 512, 0, 1);
}